// Round 3
// baseline (70.782 us; speedup 1.0000x reference)
//
#include <hip/hip_runtime.h>

// GSplat renderer, separable-Gaussian formulation, 3 kernels:
//  1) gs_tables: per-gaussian params + column table exG[n][w]=exp2(K dx^2),
//     row table eyG[n][h]=exp2(K dy^2), colpack[n]=op*(r,g,b,1).
//  2) gs_accum: partial planes over 8 N-parts. Block = 4 rows x 64 cols,
//     wave = 1 row x 64 cols (row scalarized via readfirstlane so ey/col are
//     s_loads). Inner loop per (n,pixel): 1 mul + 4 fma — the VALU floor.
//  3) gs_finalize: sum 8 parts, divide, clip. One channel per block-row.

constexpr int HH = 256;
constexpr int WW = 256;
constexpr int PIX = HH * WW;
constexpr float COORD_STEP = 2.0f / 255.0f;  // linspace(-1,1,256) step

__global__ __launch_bounds__(256) void gs_tables(
    const float* __restrict__ means, const float* __restrict__ scales,
    const float* __restrict__ opac, const float* __restrict__ colors,
    float* __restrict__ exG, float* __restrict__ eyG,
    float4* __restrict__ colpack) {
  int n = blockIdx.x;
  int t = threadIdx.x;
  // All 256 threads redo the tiny per-gaussian math (broadcast loads, ~free).
  float mx = means[3 * n + 0], my = means[3 * n + 1], mz = means[3 * n + 2];
  float scl = fmaxf((scales[3 * n + 0] + scales[3 * n + 1] + scales[3 * n + 2]) * (1.0f / 3.0f), 1e-4f);
  float op = opac[n];
  float zs = fabsf(mz) + 1.0f;
  float rzs = 1.0f / zs;
  float px = tanhf(mx * rzs);
  float py = tanhf(my * rzs);
  float sigma = fminf(fmaxf(scl * rzs, 0.02f), 0.5f);
  float inv_s = 1.0f / sigma;
  float K = -0.72134752044f * inv_s * inv_s;  // -0.5/ln2 * inv_s^2
  float c = -1.0f + COORD_STEP * (float)t;
  float dx = c - px;
  exG[n * WW + t] = exp2f(K * dx * dx);
  float dy = c - py;
  eyG[n * HH + t] = exp2f(K * dy * dy);
  if (t == 0) {
    colpack[n] = make_float4(op * colors[3 * n + 0], op * colors[3 * n + 1],
                             op * colors[3 * n + 2], op);
  }
}

// grid = (WW/64, HH/4, parts); block = 256 = 4 waves; wave w -> row by*4+w.
__global__ __launch_bounds__(256) void gs_accum(
    const float* __restrict__ exG, const float* __restrict__ eyG,
    const float4* __restrict__ colpack, float* __restrict__ partials,
    int nchunk) {
  int col = (blockIdx.x << 6) + (threadIdx.x & 63);
  int rq = __builtin_amdgcn_readfirstlane(threadIdx.x >> 6);  // wave id 0..3
  int row = (blockIdx.y << 2) + rq;
  int part = blockIdx.z;
  int n0 = part * nchunk;

  const float* exp_ptr = exG + (size_t)n0 * WW + col;
  const float* eyp = eyG + (size_t)n0 * HH + row;
  const float4* cp = colpack + n0;

  float a0 = 0.f, a1 = 0.f, a2 = 0.f, a3 = 0.f;
  for (int i = 0; i < nchunk; i += 4) {
    float ex0 = exp_ptr[0 * WW];
    float ex1 = exp_ptr[1 * WW];
    float ex2 = exp_ptr[2 * WW];
    float ex3 = exp_ptr[3 * WW];
    float ey0 = eyp[0 * HH];
    float ey1 = eyp[1 * HH];
    float ey2 = eyp[2 * HH];
    float ey3 = eyp[3 * HH];
    float4 c0 = cp[0];
    float4 c1 = cp[1];
    float4 c2 = cp[2];
    float4 c3 = cp[3];
    float w0 = ey0 * ex0;
    a0 = fmaf(w0, c0.x, a0); a1 = fmaf(w0, c0.y, a1);
    a2 = fmaf(w0, c0.z, a2); a3 = fmaf(w0, c0.w, a3);
    float w1 = ey1 * ex1;
    a0 = fmaf(w1, c1.x, a0); a1 = fmaf(w1, c1.y, a1);
    a2 = fmaf(w1, c1.z, a2); a3 = fmaf(w1, c1.w, a3);
    float w2 = ey2 * ex2;
    a0 = fmaf(w2, c2.x, a0); a1 = fmaf(w2, c2.y, a1);
    a2 = fmaf(w2, c2.z, a2); a3 = fmaf(w2, c2.w, a3);
    float w3 = ey3 * ex3;
    a0 = fmaf(w3, c3.x, a0); a1 = fmaf(w3, c3.y, a1);
    a2 = fmaf(w3, c3.z, a2); a3 = fmaf(w3, c3.w, a3);
    exp_ptr += 4 * WW;
    eyp += 4 * HH;
    cp += 4;
  }

  float* pb = partials + (size_t)part * 4 * PIX + row * WW + col;
  pb[0 * PIX] = a0;
  pb[1 * PIX] = a1;
  pb[2 * PIX] = a2;
  pb[3 * PIX] = a3;
}

// grid = (PIX/4/256, 3); each thread: one float4-group of one channel.
__global__ __launch_bounds__(256) void gs_finalize(
    const float4* __restrict__ partials4, float4* __restrict__ out4,
    int parts) {
  int g = blockIdx.x * 256 + threadIdx.x;  // 0..PIX/4-1
  int ch = blockIdx.y;                     // 0..2
  float nx = 0.f, ny = 0.f, nz = 0.f, nw = 0.f;
  float dx = 0.f, dy = 0.f, dz = 0.f, dw = 0.f;
  const float4* np = partials4 + (size_t)ch * (PIX / 4) + g;
  const float4* dp = partials4 + (size_t)3 * (PIX / 4) + g;
#pragma unroll 4
  for (int p = 0; p < parts; ++p) {
    float4 a = *np;
    float4 b = *dp;
    nx += a.x; ny += a.y; nz += a.z; nw += a.w;
    dx += b.x; dy += b.y; dz += b.z; dw += b.w;
    np += 4 * (PIX / 4);
    dp += 4 * (PIX / 4);
  }
  float4 o;
  o.x = fminf(fmaxf(nx / fmaxf(dx, 1e-5f), 0.0f), 1.0f);
  o.y = fminf(fmaxf(ny / fmaxf(dy, 1e-5f), 0.0f), 1.0f);
  o.z = fminf(fmaxf(nz / fmaxf(dz, 1e-5f), 0.0f), 1.0f);
  o.w = fminf(fmaxf(nw / fmaxf(dw, 1e-5f), 0.0f), 1.0f);
  out4[(size_t)ch * (PIX / 4) + g] = o;
}

extern "C" void kernel_launch(void* const* d_in, const int* in_sizes, int n_in,
                              void* d_out, int out_size, void* d_ws, size_t ws_size,
                              hipStream_t stream) {
  const float* means = (const float*)d_in[0];
  // d_in[1] = quats (unused by reference)
  const float* scales = (const float*)d_in[2];
  const float* opac = (const float*)d_in[3];
  const float* colors = (const float*)d_in[4];
  float* out = (float*)d_out;
  int N = in_sizes[0] / 3;  // 2048

  // Workspace layout (16B-aligned):
  //   exG      [N][WW] float
  //   eyG      [N][HH] float
  //   colpack  [N] float4
  //   partials [parts][4][PIX] float
  char* ws = (char*)d_ws;
  float* exG = (float*)ws;
  float* eyG = (float*)(ws + (size_t)N * WW * 4);
  float4* colpack = (float4*)(ws + (size_t)N * (WW + HH) * 4);
  size_t base = (size_t)N * (WW + HH) * 4 + (size_t)N * 16;
  float* partials = (float*)(ws + base);

  // Largest power-of-2 parts (<=8) whose partial planes fit the workspace.
  int parts = 1;
  for (int p = 8; p >= 1; p >>= 1) {
    if (base + (size_t)p * 4 * PIX * 4 <= ws_size) { parts = p; break; }
  }
  int nchunk = N / parts;

  gs_tables<<<N, 256, 0, stream>>>(means, scales, opac, colors, exG, eyG, colpack);
  gs_accum<<<dim3(WW / 64, HH / 4, parts), 256, 0, stream>>>(
      exG, eyG, colpack, partials, nchunk);
  gs_finalize<<<dim3(PIX / 4 / 256, 3), 256, 0, stream>>>(
      (const float4*)partials, (float4*)out, parts);
}

// Round 4
// 38.953 us; speedup vs baseline: 1.8171x; 1.8171x over previous
//
#include <hip/hip_runtime.h>

// GSplat renderer, separable-Gaussian formulation, 3 kernels:
//  1) gs_tables: exG[n][w]=exp2(K dx^2), eyG[n][h]=exp2(K dy^2),
//     colpack[n]=op*(r,g,b,1).
//  2) gs_accum: wave = 64 cols x 8 rows, per-thread acc[8][4] (32 VGPR) so
//     compute-per-load is ~320cy per 4 ex loads — latency-proof by ILP,
//     not occupancy (R3 lesson: 5 ops/load was latency-bound at any occ).
//     ey = one s_load_dwordx8 per n, col = s_load_dwordx4.
//  3) gs_finalize: sum 16 parts, divide, clip.

constexpr int HH = 256;
constexpr int WW = 256;
constexpr int PIX = HH * WW;
constexpr float COORD_STEP = 2.0f / 255.0f;  // linspace(-1,1,256) step

__global__ __launch_bounds__(256) void gs_tables(
    const float* __restrict__ means, const float* __restrict__ scales,
    const float* __restrict__ opac, const float* __restrict__ colors,
    float* __restrict__ exG, float* __restrict__ eyG,
    float4* __restrict__ colpack) {
  int n = blockIdx.x;
  int t = threadIdx.x;
  float mx = means[3 * n + 0], my = means[3 * n + 1], mz = means[3 * n + 2];
  float scl = fmaxf((scales[3 * n + 0] + scales[3 * n + 1] + scales[3 * n + 2]) * (1.0f / 3.0f), 1e-4f);
  float op = opac[n];
  float zs = fabsf(mz) + 1.0f;
  float rzs = 1.0f / zs;
  float px = tanhf(mx * rzs);
  float py = tanhf(my * rzs);
  float sigma = fminf(fmaxf(scl * rzs, 0.02f), 0.5f);
  float inv_s = 1.0f / sigma;
  float K = -0.72134752044f * inv_s * inv_s;  // -0.5/ln2 * inv_s^2
  float c = -1.0f + COORD_STEP * (float)t;
  float dx = c - px;
  exG[n * WW + t] = exp2f(K * dx * dx);
  float dy = c - py;
  eyG[n * HH + t] = exp2f(K * dy * dy);
  if (t == 0) {
    colpack[n] = make_float4(op * colors[3 * n + 0], op * colors[3 * n + 1],
                             op * colors[3 * n + 2], op);
  }
}

// grid = (WW/64, HH/32, parts); block = 256 = 4 waves.
// Wave rq: rows [by*32 + rq*8, +8), cols [bx*64, +64).
__global__ __launch_bounds__(256) void gs_accum(
    const float* __restrict__ exG, const float* __restrict__ eyG,
    const float4* __restrict__ colpack, float* __restrict__ partials,
    int nchunk) {
  int col = (blockIdx.x << 6) + (threadIdx.x & 63);
  int rq = __builtin_amdgcn_readfirstlane(threadIdx.x >> 6);  // wave id 0..3
  int row0 = (blockIdx.y << 5) + (rq << 3);
  int part = blockIdx.z;
  int n0 = part * nchunk;

  const float* exp_ptr = exG + (size_t)n0 * WW + col;
  const float* eyp = eyG + (size_t)n0 * HH + row0;  // wave-uniform
  const float4* cp = colpack + n0;                  // wave-uniform

  float acc[8][4] = {{0.f}};

  for (int i = 0; i < nchunk; i += 4) {
    float ex0 = exp_ptr[0 * WW];
    float ex1 = exp_ptr[1 * WW];
    float ex2 = exp_ptr[2 * WW];
    float ex3 = exp_ptr[3 * WW];
#define GS_N(J, EX)                                     \
    {                                                   \
      const float* ey = eyp + (J) * HH;                 \
      float4 cc = cp[J];                                \
      _Pragma("unroll")                                 \
      for (int r = 0; r < 8; ++r) {                     \
        float wt = ey[r] * (EX);                        \
        acc[r][0] = fmaf(wt, cc.x, acc[r][0]);          \
        acc[r][1] = fmaf(wt, cc.y, acc[r][1]);          \
        acc[r][2] = fmaf(wt, cc.z, acc[r][2]);          \
        acc[r][3] = fmaf(wt, cc.w, acc[r][3]);          \
      }                                                 \
    }
    GS_N(0, ex0)
    GS_N(1, ex1)
    GS_N(2, ex2)
    GS_N(3, ex3)
#undef GS_N
    exp_ptr += 4 * WW;
    eyp += 4 * HH;
    cp += 4;
  }

  float* pb = partials + (size_t)part * 4 * PIX + col;
#pragma unroll
  for (int r = 0; r < 8; ++r) {
#pragma unroll
    for (int c = 0; c < 4; ++c) {
      pb[c * PIX + (row0 + r) * WW] = acc[r][c];
    }
  }
}

// grid = (PIX/4/256, 3); each thread: one float4-group of one channel.
__global__ __launch_bounds__(256) void gs_finalize(
    const float4* __restrict__ partials4, float4* __restrict__ out4,
    int parts) {
  int g = blockIdx.x * 256 + threadIdx.x;  // 0..PIX/4-1
  int ch = blockIdx.y;                     // 0..2
  float nx = 0.f, ny = 0.f, nz = 0.f, nw = 0.f;
  float dx = 0.f, dy = 0.f, dz = 0.f, dw = 0.f;
  const float4* np = partials4 + (size_t)ch * (PIX / 4) + g;
  const float4* dp = partials4 + (size_t)3 * (PIX / 4) + g;
#pragma unroll 4
  for (int p = 0; p < parts; ++p) {
    float4 a = *np;
    float4 b = *dp;
    nx += a.x; ny += a.y; nz += a.z; nw += a.w;
    dx += b.x; dy += b.y; dz += b.z; dw += b.w;
    np += 4 * (PIX / 4);
    dp += 4 * (PIX / 4);
  }
  float4 o;
  o.x = fminf(fmaxf(nx / fmaxf(dx, 1e-5f), 0.0f), 1.0f);
  o.y = fminf(fmaxf(ny / fmaxf(dy, 1e-5f), 0.0f), 1.0f);
  o.z = fminf(fmaxf(nz / fmaxf(dz, 1e-5f), 0.0f), 1.0f);
  o.w = fminf(fmaxf(nw / fmaxf(dw, 1e-5f), 0.0f), 1.0f);
  out4[(size_t)ch * (PIX / 4) + g] = o;
}

extern "C" void kernel_launch(void* const* d_in, const int* in_sizes, int n_in,
                              void* d_out, int out_size, void* d_ws, size_t ws_size,
                              hipStream_t stream) {
  const float* means = (const float*)d_in[0];
  // d_in[1] = quats (unused by reference)
  const float* scales = (const float*)d_in[2];
  const float* opac = (const float*)d_in[3];
  const float* colors = (const float*)d_in[4];
  float* out = (float*)d_out;
  int N = in_sizes[0] / 3;  // 2048

  // Workspace layout (16B-aligned):
  //   exG      [N][WW] float
  //   eyG      [N][HH] float
  //   colpack  [N] float4
  //   partials [parts][4][PIX] float
  char* ws = (char*)d_ws;
  float* exG = (float*)ws;
  float* eyG = (float*)(ws + (size_t)N * WW * 4);
  float4* colpack = (float4*)(ws + (size_t)N * (WW + HH) * 4);
  size_t base = (size_t)N * (WW + HH) * 4 + (size_t)N * 16;
  float* partials = (float*)(ws + base);

  // Largest power-of-2 parts (<=16) whose partial planes fit the workspace.
  int parts = 1;
  for (int p = 16; p >= 1; p >>= 1) {
    if (base + (size_t)p * 4 * PIX * 4 <= ws_size) { parts = p; break; }
  }
  int nchunk = N / parts;

  gs_tables<<<N, 256, 0, stream>>>(means, scales, opac, colors, exG, eyG, colpack);
  gs_accum<<<dim3(WW / 64, HH / 32, parts), 256, 0, stream>>>(
      exG, eyG, colpack, partials, nchunk);
  gs_finalize<<<dim3(PIX / 4 / 256, 3), 256, 0, stream>>>(
      (const float4*)partials, (float4*)out, parts);
}